// Round 4
// baseline (217.279 us; speedup 1.0000x reference)
//
#include <hip/hip_runtime.h>
#include <hip/hip_bf16.h>

// Problem: B=256, A=128, F=512, D=6, C=512
// out[b,a,:] = (atoms[b,a,:] + sum_j atoms[b,bonds[b,a,j],:]) @ W[deg] + bias[deg]
// deg = count(bonds != -1), in 0..5.
//
// R8: gemm rebuilt BARRIER-FREE: no LDS staging at all. A and B fragments are
//     loaded straight from global (L2-resident: A pinned per-XCD by the grid
//     decode, Wt 3 MB hot) into registers, 2-deep ping-pong with static
//     indices, fully unrolled K loop -> per-step loads are base + imm-offset
//     (zero addr VALU), compiler emits counted vmcnt per wave, NO s_barrier
//     in the K-loop. Each wave free-runs: the R6/R7 lockstep stall is gone.
//     Kept: XCD-clustered grid decode (FETCH 29 MB = ideal, verified R5-R7),
//     fused prep kernel, sum_neigh XCD chunking, T5 setprio around MFMAs.

#define NB 256
#define NA 128
#define NF 512
#define ND 6
#define NC 512
#define NATOMS (NB * NA)   // 32768

#define NT_TRANS 1536      // transpose role blocks (16 x 16 x 6)
#define NT_BUCK  32        // bucket role blocks
#define NT_SUM   8192      // sum_neigh role blocks (NATOMS/4)

typedef __attribute__((ext_vector_type(8))) short frag8;
typedef __attribute__((ext_vector_type(4))) float f32x4;

static __device__ inline unsigned short f2bu(float f) {
    __hip_bfloat16 h = __float2bfloat16(f);
    return *reinterpret_cast<unsigned short*>(&h);
}
static __device__ inline unsigned int pack2(float a, float b) {
    return (unsigned int)f2bu(a) | ((unsigned int)f2bu(b) << 16);
}

// ---------------- kernel P: fused prep (transpose_w | bucket | sum_neigh) ----
__global__ __launch_bounds__(256) void prep(
    const float* __restrict__ W, __hip_bfloat16* __restrict__ Wt,
    const int* __restrict__ bonds, int* __restrict__ counts,
    int* __restrict__ bucket,
    const float* __restrict__ atoms, __hip_bfloat16* __restrict__ summed) {
    const int bid = blockIdx.x;
    const int tid = threadIdx.x;
    __shared__ float t[32][33];
    __shared__ int lcnt[ND];
    __shared__ int lbase[ND];

    if (bid < NT_TRANS) {
        // ---- transpose role: W[d][f][c] f32 -> Wt[d][c][f] bf16 ----
        const int tx = tid & 31, ty = tid >> 5;           // 32 x 8
        const int c0 = (bid & 15) * 32;
        const int f0 = ((bid >> 4) & 15) * 32;
        const int d  = bid >> 8;
        #pragma unroll
        for (int r = 0; r < 32; r += 8)
            t[ty + r][tx] =
                W[((size_t)(d * NF + f0 + ty + r)) * NC + c0 + tx];
        __syncthreads();
        #pragma unroll
        for (int r = 0; r < 32; r += 8)
            Wt[((size_t)(d * NC + c0 + ty + r)) * NF + f0 + tx] =
                __float2bfloat16(t[tx][ty + r]);
        return;
    }
    if (bid < NT_TRANS + NT_BUCK) {
        // ---- bucket role: degree bucketing, LDS-aggregated ----
        const int b = bid - NT_TRANS;
        if (tid < ND) lcnt[tid] = 0;
        __syncthreads();
        int deg[4], loc[4], gg[4];
        #pragma unroll
        for (int i = 0; i < 4; ++i) {
            int g = b * 1024 + i * 256 + tid;
            gg[i] = g;
            int dg = 0;
            #pragma unroll
            for (int j = 0; j < ND; ++j) dg += (bonds[g * ND + j] >= 0);
            deg[i] = dg;
            loc[i] = atomicAdd(&lcnt[dg], 1);
        }
        __syncthreads();
        if (tid < ND) lbase[tid] = atomicAdd(&counts[tid], lcnt[tid]);
        __syncthreads();
        #pragma unroll
        for (int i = 0; i < 4; ++i)
            bucket[deg[i] * NATOMS + lbase[deg[i]] + loc[i]] = gg[i];
        return;
    }
    // ---- sum_neigh role: gather/sum neighbours f32 -> bf16 ----
    // XCD-chunked: each XCD owns 32 contiguous molecules -> gather L2-hits.
    const int sbid = bid - (NT_TRANS + NT_BUCK);
    const int wave = tid >> 6;
    const int lane = tid & 63;
    const int swz  = (sbid & 7) * (NT_SUM / 8) + (sbid >> 3);
    const int g    = swz * 4 + wave;          // atom index [0, 32768)
    const float4* a4 = (const float4*)atoms;  // row = 128 float4

    int   nb[ND];
    float msk[ND];
    #pragma unroll
    for (int j = 0; j < ND; ++j) {
        int n = bonds[g * ND + j];
        msk[j] = (n >= 0) ? 1.0f : 0.0f;
        nb[j]  = (n >= 0) ? n : 0;            // dummy row 0, masked out
    }
    const int rowbase = g & ~(NA - 1);        // (g / NA) * NA

    float4 s0 = a4[(size_t)g * 128 + lane];
    float4 s1 = a4[(size_t)g * 128 + 64 + lane];
    float4 v0[ND], v1[ND];
    #pragma unroll
    for (int j = 0; j < ND; ++j) {
        const size_t base = (size_t)(rowbase + nb[j]) * 128;
        v0[j] = a4[base + lane];
        v1[j] = a4[base + 64 + lane];
    }
    #pragma unroll
    for (int j = 0; j < ND; ++j) {
        s0.x = fmaf(v0[j].x, msk[j], s0.x); s0.y = fmaf(v0[j].y, msk[j], s0.y);
        s0.z = fmaf(v0[j].z, msk[j], s0.z); s0.w = fmaf(v0[j].w, msk[j], s0.w);
        s1.x = fmaf(v1[j].x, msk[j], s1.x); s1.y = fmaf(v1[j].y, msk[j], s1.y);
        s1.z = fmaf(v1[j].z, msk[j], s1.z); s1.w = fmaf(v1[j].w, msk[j], s1.w);
    }

    uint2 o0, o1;
    o0.x = pack2(s0.x, s0.y); o0.y = pack2(s0.z, s0.w);
    o1.x = pack2(s1.x, s1.y); o1.y = pack2(s1.z, s1.w);
    ((uint2*)summed)[(size_t)g * 128 + lane] = o0;
    ((uint2*)summed)[(size_t)g * 128 + 64 + lane] = o1;
}

// ---------------- kernel B: per-degree gathered GEMM, register-direct ------
// BM=BN=128. MFMA 16x16x32 bf16; 4 waves, each owns 64x64 (wy,wx).
// No LDS operand staging: per K-step (32 elems = 64 B/row) each thread loads
// its 4 A-frags + 4 B-frags (16 B each) DIRECTLY from global. All 8 loads are
// base + kt*64 imm offsets (bases folded with quad*16 once). 2-deep ping-pong
// via compile-time kt&1 under full unroll (rule #20 safe). No barriers, no
// shared LDS hazards -> waves free-run with per-wave counted vmcnt (compiler).
// A duplication: wave pairs (0,1) and (2,3) read identical A-frags; (0,2) and
// (1,3) identical B-frags -> 2x L2 traffic, 0x extra HBM (MSHR/L2 merge).
// Grid decode: L = bx+24*by; XCD L&7; each (d,m0) pair's 4 n-tiles are
// consecutive on one XCD -> A row-tile L2-resident (FETCH 29 MB, verified).
__global__ __launch_bounds__(256, 3) void gemm_deg(
    const __hip_bfloat16* __restrict__ summed, const __hip_bfloat16* __restrict__ Wt,
    const float* __restrict__ bias, const int* __restrict__ counts,
    const int* __restrict__ bucket, float* __restrict__ out) {
    const int L  = blockIdx.x + 24 * blockIdx.y;   // 0..6143
    const int q  = L >> 3;                          // per-XCD sequence
    const int p  = ((q >> 2) << 3) + (L & 7);       // (d,m0) pair, p%8 = XCD
    const int d  = p % ND;
    const int m0 = (p / ND) * 128;
    const int n0 = (q & 3) * 128;                   // 4 n-tiles consecutive per pair
    const int Md = counts[d];
    if (m0 >= Md) return;

    __shared__ int sRows[128];
    const int tid = threadIdx.x;
    if (tid < 128) {
        int r = m0 + tid;
        sRows[tid] = (r < Md) ? bucket[d * NATOMS + r] : -1;
    }
    __syncthreads();

    const int lane = tid & 63;
    const int w    = tid >> 6;
    const int quad = lane >> 4, l16 = lane & 15;
    const int wy = w >> 1, wx = w & 1;

    // fragment base addresses (quad*16 folded in); row bytes = NF*2 = 1024
    const char* smB = (const char*)summed;
    const char* wtB = (const char*)Wt + (size_t)(d * NC + n0) * (NF * 2);
    const char* pA[4];
    const char* pB[4];
    #pragma unroll
    for (int i = 0; i < 4; ++i) {
        int g = sRows[wy * 64 + i * 16 + l16];
        pA[i] = smB + (size_t)((g < 0) ? 0 : g) * 1024 + quad * 16;
    }
    #pragma unroll
    for (int j = 0; j < 4; ++j)
        pB[j] = wtB + (size_t)(wx * 64 + j * 16 + l16) * 1024 + quad * 16;

    f32x4 acc[4][4];
    #pragma unroll
    for (int i = 0; i < 4; ++i)
        #pragma unroll
        for (int j = 0; j < 4; ++j) acc[i][j] = (f32x4)0.0f;

    // 2-deep register ping-pong, fully unrolled: loads for kt+1 issue before
    // the MFMAs of kt; compiler inserts counted s_waitcnt vmcnt(N) per wave.
    frag8 aP[2][4], bP[2][4];
    #pragma unroll
    for (int i = 0; i < 4; ++i) aP[0][i] = *(const frag8*)(pA[i]);
    #pragma unroll
    for (int j = 0; j < 4; ++j) bP[0][j] = *(const frag8*)(pB[j]);

    #pragma unroll
    for (int kt = 0; kt < NF / 32; ++kt) {
        const int cur = kt & 1, nxt = cur ^ 1;
        if (kt + 1 < NF / 32) {
            #pragma unroll
            for (int i = 0; i < 4; ++i)
                aP[nxt][i] = *(const frag8*)(pA[i] + (kt + 1) * 64);
            #pragma unroll
            for (int j = 0; j < 4; ++j)
                bP[nxt][j] = *(const frag8*)(pB[j] + (kt + 1) * 64);
        }
        __builtin_amdgcn_s_setprio(1);
        #pragma unroll
        for (int i = 0; i < 4; ++i)
            #pragma unroll
            for (int j = 0; j < 4; ++j)
                acc[i][j] = __builtin_amdgcn_mfma_f32_16x16x32_bf16(
                    aP[cur][i], bP[cur][j], acc[i][j], 0, 0, 0);
        __builtin_amdgcn_s_setprio(0);
    }

    // epilogue: C/D layout col = lane&15, row = quad*4 + reg; output FLOAT32
    #pragma unroll
    for (int j = 0; j < 4; ++j) {
        const int n = n0 + wx * 64 + j * 16 + l16;
        const float bv = bias[d * NC + n];
        #pragma unroll
        for (int i = 0; i < 4; ++i) {
            #pragma unroll
            for (int r = 0; r < 4; ++r) {
                const int tr = wy * 64 + i * 16 + quad * 4 + r;
                const int g  = sRows[tr];
                if (g >= 0)
                    out[(size_t)g * NC + n] = acc[i][j][r] + bv;
            }
        }
    }
}

extern "C" void kernel_launch(void* const* d_in, const int* in_sizes, int n_in,
                              void* d_out, int out_size, void* d_ws, size_t ws_size,
                              hipStream_t stream) {
    const float* atoms = (const float*)d_in[0];
    const int*   bonds = (const int*)d_in[1];
    const float* W     = (const float*)d_in[2];
    const float* bias  = (const float*)d_in[3];
    float* out = (float*)d_out;

    // workspace layout
    char* ws = (char*)d_ws;
    int* counts = (int*)ws;                                   // 6 ints
    int* bucket = (int*)(ws + 1024);                          // 6*32768 ints = 786432 B
    __hip_bfloat16* Wt     = (__hip_bfloat16*)(ws + 1024 + 786432);            // 3 MB
    __hip_bfloat16* summed = (__hip_bfloat16*)(ws + 1024 + 786432 + 3145728);  // 32 MB

    hipMemsetAsync(counts, 0, 1024, stream);

    prep<<<NT_TRANS + NT_BUCK + NT_SUM, 256, 0, stream>>>(
        W, Wt, bonds, counts, bucket, atoms, summed);

    gemm_deg<<<dim3(24, NATOMS / 128), 256, 0, stream>>>(
        summed, Wt, bias, counts, bucket, out);
}

// Round 5
// 174.687 us; speedup vs baseline: 1.2438x; 1.2438x over previous
//
#include <hip/hip_runtime.h>
#include <hip/hip_bf16.h>

// Problem: B=256, A=128, F=512, D=6, C=512
// out[b,a,:] = (atoms[b,a,:] + sum_j atoms[b,bonds[b,a,j],:]) @ W[deg] + bias[deg]
// deg = count(bonds != -1), in 0..5.
//
// R9: VMEM-request model (calibrated on R7=50us/R8=90us): gathered 16B lane
//     requests issue at ~1/cyc/CU — both gemm and sum_neigh are request-bound.
//     (1) gemm: BM=256,BN=128, 512 thr / 8 waves: staged bytes 402->200 MB
//         (B staged by half the blocks); 3 async16/thread/K-step; 3-buf
//         counted-vmcnt(3) single-barrier pipeline (R7-verified); LDS 73.7 KB
//         -> 2 blocks/CU = 16 waves/CU. Same 0-conflict swizzle + XCD decode.
//     (2) sum_neigh -> sum_mol: one block per molecule; stage 256 KB f32
//         molecule DENSELY (coalesced) into 128 KB bf16 LDS (XOR chunk
//         swizzle), gather+sum from LDS: 29M global requests -> 4M + LDS.
//     (3) transpose+bucket in a separate small prep_misc kernel.

#define NB 256
#define NA 128
#define NF 512
#define ND 6
#define NC 512
#define NATOMS (NB * NA)   // 32768

#define NT_TRANS 1536      // transpose role blocks (16 x 16 x 6)
#define NT_BUCK  32        // bucket role blocks

typedef __attribute__((ext_vector_type(8))) short frag8;
typedef __attribute__((ext_vector_type(4))) float f32x4;

static __device__ inline unsigned short f2bu(float f) {
    __hip_bfloat16 h = __float2bfloat16(f);
    return *reinterpret_cast<unsigned short*>(&h);
}
static __device__ inline unsigned int pack2(float a, float b) {
    return (unsigned int)f2bu(a) | ((unsigned int)f2bu(b) << 16);
}
static __device__ inline float b2f(unsigned short u) {
    __hip_bfloat16 h;
    *reinterpret_cast<unsigned short*>(&h) = u;
    return __bfloat162float(h);
}
static __device__ inline void async16(const void* g, void* l) {
    __builtin_amdgcn_global_load_lds(
        (const __attribute__((address_space(1))) void*)g,
        (__attribute__((address_space(3))) void*)l, 16, 0, 0);
}

// ---------------- kernel M: prep_misc (transpose_w | bucket_atoms) ----------
__global__ __launch_bounds__(256) void prep_misc(
    const float* __restrict__ W, __hip_bfloat16* __restrict__ Wt,
    const int* __restrict__ bonds, int* __restrict__ counts,
    int* __restrict__ bucket) {
    const int bid = blockIdx.x;
    const int tid = threadIdx.x;
    __shared__ float t[32][33];
    __shared__ int lcnt[ND];
    __shared__ int lbase[ND];

    if (bid < NT_TRANS) {
        // ---- transpose role: W[d][f][c] f32 -> Wt[d][c][f] bf16 ----
        const int tx = tid & 31, ty = tid >> 5;           // 32 x 8
        const int c0 = (bid & 15) * 32;
        const int f0 = ((bid >> 4) & 15) * 32;
        const int d  = bid >> 8;
        #pragma unroll
        for (int r = 0; r < 32; r += 8)
            t[ty + r][tx] =
                W[((size_t)(d * NF + f0 + ty + r)) * NC + c0 + tx];
        __syncthreads();
        #pragma unroll
        for (int r = 0; r < 32; r += 8)
            Wt[((size_t)(d * NC + c0 + ty + r)) * NF + f0 + tx] =
                __float2bfloat16(t[tx][ty + r]);
        return;
    }
    // ---- bucket role: degree bucketing, LDS-aggregated ----
    const int b = bid - NT_TRANS;
    if (tid < ND) lcnt[tid] = 0;
    __syncthreads();
    int deg[4], loc[4], gg[4];
    #pragma unroll
    for (int i = 0; i < 4; ++i) {
        int g = b * 1024 + i * 256 + tid;
        gg[i] = g;
        int dg = 0;
        #pragma unroll
        for (int j = 0; j < ND; ++j) dg += (bonds[g * ND + j] >= 0);
        deg[i] = dg;
        loc[i] = atomicAdd(&lcnt[dg], 1);
    }
    __syncthreads();
    if (tid < ND) lbase[tid] = atomicAdd(&counts[tid], lcnt[tid]);
    __syncthreads();
    #pragma unroll
    for (int i = 0; i < 4; ++i)
        bucket[deg[i] * NATOMS + lbase[deg[i]] + loc[i]] = gg[i];
}

// ---------------- kernel A: sum_mol — whole-molecule gather in LDS ----------
// One block per molecule. Stage: molecule atoms (256 KB f32) read DENSELY
// (coalesced float4) -> bf16 -> LDS [128 rows][64 chunks of 16B], chunk
// XOR-swizzled (phys = c ^ (row&7)) so random-row gather reads spread banks.
// Compute: thread owns (atom a = tid>>2, quarter qd = tid&3): for each 16B
// chunk, sum self + 6 masked neighbour chunks from LDS in f32, pack bf16.
__global__ __launch_bounds__(512, 2) void sum_mol(
    const float* __restrict__ atoms, const int* __restrict__ bonds,
    __hip_bfloat16* __restrict__ summed) {
    __shared__ __align__(16) __hip_bfloat16 mol[NA * NF];   // 128 KB
    char* molB = (char*)mol;
    const int m   = blockIdx.x;
    const int tid = threadIdx.x;

    // ---- stage: dense coalesced read, swizzled LDS write (conflict-free) ----
    const float4* a4 = (const float4*)atoms + (size_t)m * (NA * NF / 4);
    #pragma unroll 4
    for (int i = 0; i < 32; ++i) {
        float4 v = a4[i * 512 + tid];
        const int r  = i * 4 + (tid >> 7);
        const int co = tid & 127;              // float4 index within row
        uint2 pk; pk.x = pack2(v.x, v.y); pk.y = pack2(v.z, v.w);
        *(uint2*)(molB + r * 1024 + (((co >> 1) ^ (r & 7)) << 4) + (co & 1) * 8) = pk;
    }
    __syncthreads();

    // ---- gather+sum from LDS ----
    const int a  = tid >> 2;                   // atom 0..127
    const int qd = tid & 3;                    // quarter of the feature row
    const int* bd = bonds + (size_t)(m * NA + a) * ND;
    int   nb[ND], x7[ND];
    float msk[ND];
    #pragma unroll
    for (int j = 0; j < ND; ++j) {
        int n = bd[j];
        msk[j] = (n >= 0) ? 1.0f : 0.0f;
        nb[j]  = (n >= 0) ? n : 0;
        x7[j]  = nb[j] & 7;
    }
    const int a7 = a & 7;
    char* outB = (char*)summed + (size_t)(m * NA + a) * 1024;

    #pragma unroll 4
    for (int ci = 0; ci < 16; ++ci) {
        const int c = qd * 16 + ci;
        const frag8 s = *(const frag8*)(molB + a * 1024 + ((c ^ a7) << 4));
        float acc[8];
        #pragma unroll
        for (int e = 0; e < 8; ++e) acc[e] = b2f((unsigned short)s[e]);
        #pragma unroll
        for (int j = 0; j < ND; ++j) {
            const frag8 v = *(const frag8*)(molB + nb[j] * 1024 + ((c ^ x7[j]) << 4));
            #pragma unroll
            for (int e = 0; e < 8; ++e)
                acc[e] = fmaf(b2f((unsigned short)v[e]), msk[j], acc[e]);
        }
        uint4 o;
        o.x = pack2(acc[0], acc[1]); o.y = pack2(acc[2], acc[3]);
        o.z = pack2(acc[4], acc[5]); o.w = pack2(acc[6], acc[7]);
        *(uint4*)(outB + c * 16) = o;
    }
}

// ---------------- kernel B: per-degree gathered GEMM ----------------
// BM=256, BN=128, BK=32. 512 threads / 8 waves (4m x 2n), wave tile 64x64.
// Triple-buffered, 2-tile-ahead counted-vmcnt pipeline, ONE barrier/K-step:
//   prologue: stage(t0->buf0), stage(t1->buf1)           [3 async16/thread]
//   iter kt: wait vmcnt(3) [kt landed, kt+1 in flight] -> s_barrier ->
//            stage(kt+2 -> buf (kt+2)%3) -> setprio(1) MFMA(kt) setprio(0)
// LDS swizzle (R7-verified, 0 conflicts): LDS[row][slot] holds global seg
// slot ^ ((row>>1)&3); pre-swizzled on the GLOBAL source (rule 21), linear
// gload_lds dest; read slot = quad ^ ((l16>>1)&3).
// Grid decode (XCD-bijective, R5-verified): L = bx + 24*by over (24,128);
// pair p = (d, 256-row m-tile) lands on XCD p&7 with its 4 n-tiles at
// consecutive q -> A row-tile L2-resident. B staged by half the blocks of R7.
__global__ __launch_bounds__(512, 4) void gemm_deg(
    const __hip_bfloat16* __restrict__ summed, const __hip_bfloat16* __restrict__ Wt,
    const float* __restrict__ bias, const int* __restrict__ counts,
    const int* __restrict__ bucket, float* __restrict__ out) {
    const int L  = blockIdx.x + 24 * blockIdx.y;   // 0..3071
    const int q  = L >> 3;                          // per-XCD sequence
    const int p  = ((q >> 2) << 3) + (L & 7);       // 0..767: (d, m-tile) pair
    const int d  = p % ND;
    const int m0 = (p / ND) * 256;
    const int n0 = (q & 3) * 128;                   // 4 n-tiles consecutive per pair
    const int Md = counts[d];
    if (m0 >= Md) return;

    __shared__ __align__(16) __hip_bfloat16 sA[3][256 * 32];  // 48 KB, swizzled
    __shared__ __align__(16) __hip_bfloat16 sB[3][128 * 32];  // 24 KB (Wt rows)
    __shared__ int sRows[256];

    const int tid = threadIdx.x;
    if (tid < 256) {
        int r = m0 + tid;
        sRows[tid] = (r < Md) ? bucket[d * NATOMS + r] : -1;
    }
    __syncthreads();

    const int lane = tid & 63;
    const int w    = tid >> 6;      // 0..7

    // staging coords: lane covers (row = base + sr, slot sl); 16 rows/wave/chunk
    const int sr = lane >> 2;       // 0..15
    const int sl = lane & 3;
    const int gseg = sl ^ ((sr >> 1) & 3);   // bases are mult of 16 -> (row>>1)&3 = (sr>>1)&3

    const int rA0 = w * 16 + sr;             // A rows 0..127
    const int rA1 = 128 + rA0;               // A rows 128..255
    const int rB  = w * 16 + sr;             // B rows 0..127
    const char* smB = (const char*)summed;
    const char* wtB = (const char*)Wt + (size_t)(d * NC + n0) * 1024;
    int g0 = sRows[rA0], g1 = sRows[rA1];
    const size_t gA0 = (size_t)((g0 < 0) ? 0 : g0) * 1024;   // dummy row 0
    const size_t gA1 = (size_t)((g1 < 0) ? 0 : g1) * 1024;
    const size_t gB  = (size_t)rB * 1024;

    const int quad = lane >> 4, l16 = lane & 15;
    const int xr2  = (l16 >> 1) & 3;         // read-side swizzle
    const int wy = w >> 1, wx = w & 1;

    f32x4 acc[4][4];
    #pragma unroll
    for (int i = 0; i < 4; ++i)
        #pragma unroll
        for (int j = 0; j < 4; ++j) acc[i][j] = (f32x4)0.0f;

    // wave-uniform LDS dests (HW adds lane*16): A chunk c at rows c*128+w*16
    auto stage = [&](int buf, int kt) {
        const int koff = kt * 64 + gseg * 16;
        async16(smB + gA0 + koff, (char*)&sA[buf][0] + w * 1024);
        async16(smB + gA1 + koff, (char*)&sA[buf][0] + 8192 + w * 1024);
        async16(wtB + gB  + koff, (char*)&sB[buf][0] + w * 1024);
    };
    auto compute = [&](int buf) {
        frag8 aF[4], bF[4];
        #pragma unroll
        for (int i = 0; i < 4; ++i)
            aF[i] = *(const frag8*)&sA[buf][(wy * 64 + i * 16 + l16) * 32 +
                                            ((quad ^ xr2) << 3)];
        #pragma unroll
        for (int j = 0; j < 4; ++j)
            bF[j] = *(const frag8*)&sB[buf][(wx * 64 + j * 16 + l16) * 32 +
                                            ((quad ^ xr2) << 3)];
        #pragma unroll
        for (int i = 0; i < 4; ++i)
            #pragma unroll
            for (int j = 0; j < 4; ++j)
                acc[i][j] = __builtin_amdgcn_mfma_f32_16x16x32_bf16(
                    aF[i], bF[j], acc[i][j], 0, 0, 0);
    };

    stage(0, 0);                                   // tile 0 -> buf 0
    stage(1, 1);                                   // tile 1 -> buf 1
    #pragma unroll
    for (int kt = 0; kt < NF / 32; ++kt) {
        if (kt < NF / 32 - 1)
            asm volatile("s_waitcnt vmcnt(3)" ::: "memory");  // tile kt landed
        else
            asm volatile("s_waitcnt vmcnt(0)" ::: "memory");
        __builtin_amdgcn_sched_barrier(0);
        __builtin_amdgcn_s_barrier();              // tile kt visible; buf kt+2 free
        if (kt + 2 < NF / 32) stage((kt + 2) % 3, kt + 2);
        __builtin_amdgcn_s_setprio(1);
        compute(kt % 3);
        __builtin_amdgcn_s_setprio(0);
    }

    // epilogue: C/D layout col = lane&15, row = quad*4 + reg; output FLOAT32
    #pragma unroll
    for (int j = 0; j < 4; ++j) {
        const int n = n0 + wx * 64 + j * 16 + l16;
        const float bv = bias[d * NC + n];
        #pragma unroll
        for (int i = 0; i < 4; ++i) {
            #pragma unroll
            for (int r = 0; r < 4; ++r) {
                const int tr = wy * 64 + i * 16 + quad * 4 + r;
                const int g  = sRows[tr];
                if (g >= 0)
                    out[(size_t)g * NC + n] = acc[i][j][r] + bv;
            }
        }
    }
}

extern "C" void kernel_launch(void* const* d_in, const int* in_sizes, int n_in,
                              void* d_out, int out_size, void* d_ws, size_t ws_size,
                              hipStream_t stream) {
    const float* atoms = (const float*)d_in[0];
    const int*   bonds = (const int*)d_in[1];
    const float* W     = (const float*)d_in[2];
    const float* bias  = (const float*)d_in[3];
    float* out = (float*)d_out;

    // workspace layout
    char* ws = (char*)d_ws;
    int* counts = (int*)ws;                                   // 6 ints
    int* bucket = (int*)(ws + 1024);                          // 6*32768 ints = 786432 B
    __hip_bfloat16* Wt     = (__hip_bfloat16*)(ws + 1024 + 786432);            // 3 MB
    __hip_bfloat16* summed = (__hip_bfloat16*)(ws + 1024 + 786432 + 3145728);  // 32 MB

    hipMemsetAsync(counts, 0, 1024, stream);

    prep_misc<<<NT_TRANS + NT_BUCK, 256, 0, stream>>>(W, Wt, bonds, counts, bucket);

    sum_mol<<<NB, 512, 0, stream>>>(atoms, bonds, summed);

    gemm_deg<<<dim3(24, 128), 512, 0, stream>>>(
        summed, Wt, bias, counts, bucket, out);
}

// Round 6
// 171.871 us; speedup vs baseline: 1.2642x; 1.0164x over previous
//
#include <hip/hip_runtime.h>
#include <hip/hip_bf16.h>

// Problem: B=256, A=128, F=512, D=6, C=512
// out[b,a,:] = (atoms[b,a,:] + sum_j atoms[b,bonds[b,a,j],:]) @ W[deg] + bias[deg]
// deg = count(bonds != -1), in 0..5.
//
// R10: write-path round. Evidence: 5 structurally different gemms all pin at
//      ~1.5-1.7 TB/s write-dominated HBM with WRITE_SIZE 1.28x ideal -> the
//      scattered 64B-segment epilogue (rows split 4 ways, line halves 16
//      stores apart, L2-eviction-ordered) is the binding constraint.
//      (1) BN=256 (2 n-tiles/pair): each block owns 1 KB per out-row; per
//          wave 4 j-segments are 256 B contiguous. BM=128 -> 516 working
//          blocks = 2/CU. LDS 72.5 KB -> 2 blocks/CU.
//      (2) epilogue j-inner + __builtin_nontemporal_store: line halves
//          back-to-back, HBM sees program-ordered streams, out stays out of
//          L2 (protects resident summed/Wt).
//      Kept (verified): 3-buf counted-vmcnt(3) 1-barrier pipeline, 0-conflict
//      swizzle, XCD-bijective grid decode, sum_mol LDS gather, prep_misc.

#define NB 256
#define NA 128
#define NF 512
#define ND 6
#define NC 512
#define NATOMS (NB * NA)   // 32768

#define NT_TRANS 1536      // transpose role blocks (16 x 16 x 6)
#define NT_BUCK  32        // bucket role blocks

typedef __attribute__((ext_vector_type(8))) short frag8;
typedef __attribute__((ext_vector_type(4))) float f32x4;

static __device__ inline unsigned short f2bu(float f) {
    __hip_bfloat16 h = __float2bfloat16(f);
    return *reinterpret_cast<unsigned short*>(&h);
}
static __device__ inline unsigned int pack2(float a, float b) {
    return (unsigned int)f2bu(a) | ((unsigned int)f2bu(b) << 16);
}
static __device__ inline float b2f(unsigned short u) {
    __hip_bfloat16 h;
    *reinterpret_cast<unsigned short*>(&h) = u;
    return __bfloat162float(h);
}
static __device__ inline void async16(const void* g, void* l) {
    __builtin_amdgcn_global_load_lds(
        (const __attribute__((address_space(1))) void*)g,
        (__attribute__((address_space(3))) void*)l, 16, 0, 0);
}

// ---------------- kernel M: prep_misc (transpose_w | bucket_atoms) ----------
__global__ __launch_bounds__(256) void prep_misc(
    const float* __restrict__ W, __hip_bfloat16* __restrict__ Wt,
    const int* __restrict__ bonds, int* __restrict__ counts,
    int* __restrict__ bucket) {
    const int bid = blockIdx.x;
    const int tid = threadIdx.x;
    __shared__ float t[32][33];
    __shared__ int lcnt[ND];
    __shared__ int lbase[ND];

    if (bid < NT_TRANS) {
        // ---- transpose role: W[d][f][c] f32 -> Wt[d][c][f] bf16 ----
        const int tx = tid & 31, ty = tid >> 5;           // 32 x 8
        const int c0 = (bid & 15) * 32;
        const int f0 = ((bid >> 4) & 15) * 32;
        const int d  = bid >> 8;
        #pragma unroll
        for (int r = 0; r < 32; r += 8)
            t[ty + r][tx] =
                W[((size_t)(d * NF + f0 + ty + r)) * NC + c0 + tx];
        __syncthreads();
        #pragma unroll
        for (int r = 0; r < 32; r += 8)
            Wt[((size_t)(d * NC + c0 + ty + r)) * NF + f0 + tx] =
                __float2bfloat16(t[tx][ty + r]);
        return;
    }
    // ---- bucket role: degree bucketing, LDS-aggregated ----
    const int b = bid - NT_TRANS;
    if (tid < ND) lcnt[tid] = 0;
    __syncthreads();
    int deg[4], loc[4], gg[4];
    #pragma unroll
    for (int i = 0; i < 4; ++i) {
        int g = b * 1024 + i * 256 + tid;
        gg[i] = g;
        int dg = 0;
        #pragma unroll
        for (int j = 0; j < ND; ++j) dg += (bonds[g * ND + j] >= 0);
        deg[i] = dg;
        loc[i] = atomicAdd(&lcnt[dg], 1);
    }
    __syncthreads();
    if (tid < ND) lbase[tid] = atomicAdd(&counts[tid], lcnt[tid]);
    __syncthreads();
    #pragma unroll
    for (int i = 0; i < 4; ++i)
        bucket[deg[i] * NATOMS + lbase[deg[i]] + loc[i]] = gg[i];
}

// ---------------- kernel A: sum_mol — whole-molecule gather in LDS ----------
// One block per molecule. Stage 256 KB f32 molecule densely (coalesced) into
// 128 KB bf16 LDS (chunk XOR-swizzle), then gather+sum 6 neighbours from LDS.
__global__ __launch_bounds__(512, 2) void sum_mol(
    const float* __restrict__ atoms, const int* __restrict__ bonds,
    __hip_bfloat16* __restrict__ summed) {
    __shared__ __align__(16) __hip_bfloat16 mol[NA * NF];   // 128 KB
    char* molB = (char*)mol;
    const int m   = blockIdx.x;
    const int tid = threadIdx.x;

    // ---- stage: dense coalesced read, swizzled LDS write (conflict-free) ----
    const float4* a4 = (const float4*)atoms + (size_t)m * (NA * NF / 4);
    #pragma unroll 4
    for (int i = 0; i < 32; ++i) {
        float4 v = a4[i * 512 + tid];
        const int r  = i * 4 + (tid >> 7);
        const int co = tid & 127;              // float4 index within row
        uint2 pk; pk.x = pack2(v.x, v.y); pk.y = pack2(v.z, v.w);
        *(uint2*)(molB + r * 1024 + (((co >> 1) ^ (r & 7)) << 4) + (co & 1) * 8) = pk;
    }
    __syncthreads();

    // ---- gather+sum from LDS ----
    const int a  = tid >> 2;                   // atom 0..127
    const int qd = tid & 3;                    // quarter of the feature row
    const int* bd = bonds + (size_t)(m * NA + a) * ND;
    int   nb[ND], x7[ND];
    float msk[ND];
    #pragma unroll
    for (int j = 0; j < ND; ++j) {
        int n = bd[j];
        msk[j] = (n >= 0) ? 1.0f : 0.0f;
        nb[j]  = (n >= 0) ? n : 0;
        x7[j]  = nb[j] & 7;
    }
    const int a7 = a & 7;
    char* outB = (char*)summed + (size_t)(m * NA + a) * 1024;

    #pragma unroll 4
    for (int ci = 0; ci < 16; ++ci) {
        const int c = qd * 16 + ci;
        const frag8 s = *(const frag8*)(molB + a * 1024 + ((c ^ a7) << 4));
        float acc[8];
        #pragma unroll
        for (int e = 0; e < 8; ++e) acc[e] = b2f((unsigned short)s[e]);
        #pragma unroll
        for (int j = 0; j < ND; ++j) {
            const frag8 v = *(const frag8*)(molB + nb[j] * 1024 + ((c ^ x7[j]) << 4));
            #pragma unroll
            for (int e = 0; e < 8; ++e)
                acc[e] = fmaf(b2f((unsigned short)v[e]), msk[j], acc[e]);
        }
        uint4 o;
        o.x = pack2(acc[0], acc[1]); o.y = pack2(acc[2], acc[3]);
        o.z = pack2(acc[4], acc[5]); o.w = pack2(acc[6], acc[7]);
        *(uint4*)(outB + c * 16) = o;
    }
}

// ---------------- kernel B: per-degree gathered GEMM ----------------
// BM=128, BN=256, BK=32. 512 threads / 8 waves (2m x 4n), wave tile 64x64.
// Triple-buffered, 2-tile-ahead counted-vmcnt pipeline, ONE barrier/K-step:
//   prologue: stage(t0->buf0), stage(t1->buf1)           [3 async16/thread]
//   iter kt: wait vmcnt(3) [kt landed, kt+1 in flight] -> s_barrier ->
//            stage(kt+2 -> buf (kt+2)%3) -> setprio(1) MFMA(kt) setprio(0)
// LDS swizzle (0 conflicts, verified): LDS[row][slot] holds global seg
// slot ^ ((row>>1)&3); pre-swizzled on the GLOBAL source (rule 21), linear
// gload_lds dest; read slot = quad ^ ((l16>>1)&3).
// Grid decode (XCD-bijective): L = bx + 24*by; q = L>>3; pair
// p = ((q>>1)<<3) + (L&7) -> its 2 n-tiles at consecutive q on one XCD
// (A-tile L2-resident). Active blocks = first ~516 L's = 2/CU.
// Epilogue: per (i,r) row, 4 j-segments 256 B contiguous, nontemporal
// stores -> full 128 B lines, program-ordered HBM write stream.
__global__ __launch_bounds__(512, 4) void gemm_deg(
    const __hip_bfloat16* __restrict__ summed, const __hip_bfloat16* __restrict__ Wt,
    const float* __restrict__ bias, const int* __restrict__ counts,
    const int* __restrict__ bucket, float* __restrict__ out) {
    const int L  = blockIdx.x + 24 * blockIdx.y;   // 0..3071
    const int q  = L >> 3;                          // per-XCD sequence
    const int p  = ((q >> 1) << 3) + (L & 7);       // 0..1535: (d, m-tile) pair
    const int d  = p % ND;
    const int m0 = (p / ND) * 128;
    const int n0 = (q & 1) * 256;                   // 2 n-tiles consecutive per pair
    const int Md = counts[d];
    if (m0 >= Md) return;

    __shared__ __align__(16) __hip_bfloat16 sA[3][128 * 32];  // 24 KB, swizzled
    __shared__ __align__(16) __hip_bfloat16 sB[3][256 * 32];  // 48 KB (Wt rows)
    __shared__ int sRows[128];

    const int tid = threadIdx.x;
    if (tid < 128) {
        int r = m0 + tid;
        sRows[tid] = (r < Md) ? bucket[d * NATOMS + r] : -1;
    }
    __syncthreads();

    const int lane = tid & 63;
    const int w    = tid >> 6;      // 0..7

    // staging coords: lane covers (row = base + sr, 16B slot sl)
    const int sr = lane >> 2;       // 0..15
    const int sl = lane & 3;
    const int gseg = sl ^ ((sr >> 1) & 3);   // bases mult of 16 -> (row>>1)&3 = (sr>>1)&3

    const int rA = w * 16 + sr;              // A rows 0..127
    const char* smB = (const char*)summed;
    const char* wtB = (const char*)Wt + (size_t)(d * NC + n0) * 1024;
    int g0 = sRows[rA];
    const size_t gA0 = (size_t)((g0 < 0) ? 0 : g0) * 1024;   // dummy row 0
    const size_t gB0 = (size_t)(w * 16 + sr) * 1024;         // B rows 0..127
    const size_t gB1 = (size_t)(128 + w * 16 + sr) * 1024;   // B rows 128..255

    const int quad = lane >> 4, l16 = lane & 15;
    const int xr2  = (l16 >> 1) & 3;         // read-side swizzle
    const int wy = w >> 2, wx = w & 3;       // 2m x 4n wave grid

    f32x4 acc[4][4];
    #pragma unroll
    for (int i = 0; i < 4; ++i)
        #pragma unroll
        for (int j = 0; j < 4; ++j) acc[i][j] = (f32x4)0.0f;

    // wave-uniform LDS dests (HW adds lane*16)
    auto stage = [&](int buf, int kt) {
        const int koff = kt * 64 + gseg * 16;
        async16(smB + gA0 + koff, (char*)&sA[buf][0] + w * 1024);
        async16(wtB + gB0 + koff, (char*)&sB[buf][0] + w * 1024);
        async16(wtB + gB1 + koff, (char*)&sB[buf][0] + 8192 + w * 1024);
    };
    auto compute = [&](int buf) {
        frag8 aF[4], bF[4];
        #pragma unroll
        for (int i = 0; i < 4; ++i)
            aF[i] = *(const frag8*)&sA[buf][(wy * 64 + i * 16 + l16) * 32 +
                                            ((quad ^ xr2) << 3)];
        #pragma unroll
        for (int j = 0; j < 4; ++j)
            bF[j] = *(const frag8*)&sB[buf][(wx * 64 + j * 16 + l16) * 32 +
                                            ((quad ^ xr2) << 3)];
        #pragma unroll
        for (int i = 0; i < 4; ++i)
            #pragma unroll
            for (int j = 0; j < 4; ++j)
                acc[i][j] = __builtin_amdgcn_mfma_f32_16x16x32_bf16(
                    aF[i], bF[j], acc[i][j], 0, 0, 0);
    };

    stage(0, 0);                                   // tile 0 -> buf 0
    stage(1, 1);                                   // tile 1 -> buf 1
    #pragma unroll
    for (int kt = 0; kt < NF / 32; ++kt) {
        if (kt < NF / 32 - 1)
            asm volatile("s_waitcnt vmcnt(3)" ::: "memory");  // tile kt landed
        else
            asm volatile("s_waitcnt vmcnt(0)" ::: "memory");
        __builtin_amdgcn_sched_barrier(0);
        __builtin_amdgcn_s_barrier();              // tile kt visible; buf kt+2 free
        if (kt + 2 < NF / 32) stage((kt + 2) % 3, kt + 2);
        __builtin_amdgcn_s_setprio(1);
        compute(kt % 3);
        __builtin_amdgcn_s_setprio(0);
    }

    // epilogue: C/D layout col = lane&15, row = quad*4 + reg. Per (i,r) row:
    // 4 j-segments (64 B each) written back-to-back = 256 B contiguous per
    // wave, nontemporal -> full lines, ordered stream, no L2 pollution.
    float bv[4];
    #pragma unroll
    for (int j = 0; j < 4; ++j)
        bv[j] = bias[d * NC + n0 + wx * 64 + j * 16 + l16];
    #pragma unroll
    for (int i = 0; i < 4; ++i) {
        #pragma unroll
        for (int r = 0; r < 4; ++r) {
            const int tr = wy * 64 + i * 16 + quad * 4 + r;
            const int g  = sRows[tr];
            if (g < 0) continue;
            float* orow = out + (size_t)g * NC + n0 + wx * 64 + l16;
            #pragma unroll
            for (int j = 0; j < 4; ++j)
                __builtin_nontemporal_store(acc[i][j][r] + bv[j], orow + j * 16);
        }
    }
}

extern "C" void kernel_launch(void* const* d_in, const int* in_sizes, int n_in,
                              void* d_out, int out_size, void* d_ws, size_t ws_size,
                              hipStream_t stream) {
    const float* atoms = (const float*)d_in[0];
    const int*   bonds = (const int*)d_in[1];
    const float* W     = (const float*)d_in[2];
    const float* bias  = (const float*)d_in[3];
    float* out = (float*)d_out;

    // workspace layout
    char* ws = (char*)d_ws;
    int* counts = (int*)ws;                                   // 6 ints
    int* bucket = (int*)(ws + 1024);                          // 6*32768 ints = 786432 B
    __hip_bfloat16* Wt     = (__hip_bfloat16*)(ws + 1024 + 786432);            // 3 MB
    __hip_bfloat16* summed = (__hip_bfloat16*)(ws + 1024 + 786432 + 3145728);  // 32 MB

    hipMemsetAsync(counts, 0, 1024, stream);

    prep_misc<<<NT_TRANS + NT_BUCK, 256, 0, stream>>>(W, Wt, bonds, counts, bucket);

    sum_mol<<<NB, 512, 0, stream>>>(atoms, bonds, summed);

    gemm_deg<<<dim3(24, 128), 512, 0, stream>>>(
        summed, Wt, bias, counts, bucket, out);
}

// Round 7
// 166.635 us; speedup vs baseline: 1.3039x; 1.0314x over previous
//
#include <hip/hip_runtime.h>
#include <hip/hip_bf16.h>

// Problem: B=256, A=128, F=512, D=6, C=512
// out[b,a,:] = (atoms[b,a,:] + sum_j atoms[b,bonds[b,a,j],:]) @ W[deg] + bias[deg]
// deg = count(bonds != -1), in 0..5.
//
// R11: finish the write-path fix (R10 proved stores are the gemm pacer:
//      epilogue reorder alone gave 54->42 us).
//      (1) gemm: LDS-transposed epilogue. After the K-loop the 72 KB staging
//          LDS is dead; dump acc into it as [row][256 cols] f32 (two 64-row
//          slices), then each wave reads ONE row, lanes = 64 contiguous
//          float4 chunks -> nt global_store_dwordx4, 1 KB fully-dense per
//          instruction (the rocclr fill proves this stream does 6.5 TB/s).
//          Store insts 64->16 per thread, all full 128B lines.
//      (2) sum_mol: same cure. uint4 stores scattered 64x16B per inst ->
//          register-buffer the 16 chunk sums, write back into mol LDS,
//          copy out with lane=chunk mapping (1 KB contiguous per wave-inst).
//      Kept (all verified): 3-buf counted-vmcnt(3) 1-barrier pipeline,
//      0-conflict stage swizzle, XCD-bijective grid decode, BM=128/BN=256,
//      sum_mol dense-stage LDS gather, prep_misc.

#define NB 256
#define NA 128
#define NF 512
#define ND 6
#define NC 512
#define NATOMS (NB * NA)   // 32768

#define NT_TRANS 1536      // transpose role blocks (16 x 16 x 6)
#define NT_BUCK  32        // bucket role blocks

typedef __attribute__((ext_vector_type(8))) short frag8;
typedef __attribute__((ext_vector_type(4))) float f32x4;
typedef __attribute__((ext_vector_type(4))) unsigned int u32x4;

static __device__ inline unsigned short f2bu(float f) {
    __hip_bfloat16 h = __float2bfloat16(f);
    return *reinterpret_cast<unsigned short*>(&h);
}
static __device__ inline unsigned int pack2(float a, float b) {
    return (unsigned int)f2bu(a) | ((unsigned int)f2bu(b) << 16);
}
static __device__ inline float b2f(unsigned short u) {
    __hip_bfloat16 h;
    *reinterpret_cast<unsigned short*>(&h) = u;
    return __bfloat162float(h);
}
static __device__ inline void async16(const void* g, void* l) {
    __builtin_amdgcn_global_load_lds(
        (const __attribute__((address_space(1))) void*)g,
        (__attribute__((address_space(3))) void*)l, 16, 0, 0);
}

// ---------------- kernel M: prep_misc (transpose_w | bucket_atoms) ----------
__global__ __launch_bounds__(256) void prep_misc(
    const float* __restrict__ W, __hip_bfloat16* __restrict__ Wt,
    const int* __restrict__ bonds, int* __restrict__ counts,
    int* __restrict__ bucket) {
    const int bid = blockIdx.x;
    const int tid = threadIdx.x;
    __shared__ float t[32][33];
    __shared__ int lcnt[ND];
    __shared__ int lbase[ND];

    if (bid < NT_TRANS) {
        // ---- transpose role: W[d][f][c] f32 -> Wt[d][c][f] bf16 ----
        const int tx = tid & 31, ty = tid >> 5;           // 32 x 8
        const int c0 = (bid & 15) * 32;
        const int f0 = ((bid >> 4) & 15) * 32;
        const int d  = bid >> 8;
        #pragma unroll
        for (int r = 0; r < 32; r += 8)
            t[ty + r][tx] =
                W[((size_t)(d * NF + f0 + ty + r)) * NC + c0 + tx];
        __syncthreads();
        #pragma unroll
        for (int r = 0; r < 32; r += 8)
            Wt[((size_t)(d * NC + c0 + ty + r)) * NF + f0 + tx] =
                __float2bfloat16(t[tx][ty + r]);
        return;
    }
    // ---- bucket role: degree bucketing, LDS-aggregated ----
    const int b = bid - NT_TRANS;
    if (tid < ND) lcnt[tid] = 0;
    __syncthreads();
    int deg[4], loc[4], gg[4];
    #pragma unroll
    for (int i = 0; i < 4; ++i) {
        int g = b * 1024 + i * 256 + tid;
        gg[i] = g;
        int dg = 0;
        #pragma unroll
        for (int j = 0; j < ND; ++j) dg += (bonds[g * ND + j] >= 0);
        deg[i] = dg;
        loc[i] = atomicAdd(&lcnt[dg], 1);
    }
    __syncthreads();
    if (tid < ND) lbase[tid] = atomicAdd(&counts[tid], lcnt[tid]);
    __syncthreads();
    #pragma unroll
    for (int i = 0; i < 4; ++i)
        bucket[deg[i] * NATOMS + lbase[deg[i]] + loc[i]] = gg[i];
}

// ---------------- kernel A: sum_mol — whole-molecule gather in LDS ----------
// One block per molecule. Stage 256 KB f32 molecule densely (coalesced) into
// 128 KB bf16 LDS (chunk XOR-swizzle), gather+sum 6 neighbours from LDS into
// registers, write sums back into mol, then coalesced copy-out: per store
// instruction one wave covers ONE row's 1 KB contiguously (lane = chunk).
__global__ __launch_bounds__(512, 2) void sum_mol(
    const float* __restrict__ atoms, const int* __restrict__ bonds,
    __hip_bfloat16* __restrict__ summed) {
    __shared__ __align__(16) __hip_bfloat16 mol[NA * NF];   // 128 KB
    char* molB = (char*)mol;
    const int m   = blockIdx.x;
    const int tid = threadIdx.x;

    // ---- stage: dense coalesced read, swizzled LDS write (conflict-free) ----
    const float4* a4 = (const float4*)atoms + (size_t)m * (NA * NF / 4);
    #pragma unroll 4
    for (int i = 0; i < 32; ++i) {
        float4 v = a4[i * 512 + tid];
        const int r  = i * 4 + (tid >> 7);
        const int co = tid & 127;              // float4 index within row
        uint2 pk; pk.x = pack2(v.x, v.y); pk.y = pack2(v.z, v.w);
        *(uint2*)(molB + r * 1024 + (((co >> 1) ^ (r & 7)) << 4) + (co & 1) * 8) = pk;
    }
    __syncthreads();

    // ---- gather+sum from LDS into registers ----
    const int a  = tid >> 2;                   // atom 0..127
    const int qd = tid & 3;                    // quarter of the feature row
    const int* bd = bonds + (size_t)(m * NA + a) * ND;
    int   nb[ND], x7[ND];
    float msk[ND];
    #pragma unroll
    for (int j = 0; j < ND; ++j) {
        int n = bd[j];
        msk[j] = (n >= 0) ? 1.0f : 0.0f;
        nb[j]  = (n >= 0) ? n : 0;
        x7[j]  = nb[j] & 7;
    }
    const int a7 = a & 7;

    u32x4 psum[16];
    #pragma unroll
    for (int ci = 0; ci < 16; ++ci) {
        const int c = qd * 16 + ci;
        const frag8 s = *(const frag8*)(molB + a * 1024 + ((c ^ a7) << 4));
        float acc[8];
        #pragma unroll
        for (int e = 0; e < 8; ++e) acc[e] = b2f((unsigned short)s[e]);
        #pragma unroll
        for (int j = 0; j < ND; ++j) {
            const frag8 v = *(const frag8*)(molB + nb[j] * 1024 + ((c ^ x7[j]) << 4));
            #pragma unroll
            for (int e = 0; e < 8; ++e)
                acc[e] = fmaf(b2f((unsigned short)v[e]), msk[j], acc[e]);
        }
        u32x4 o;
        o[0] = pack2(acc[0], acc[1]); o[1] = pack2(acc[2], acc[3]);
        o[2] = pack2(acc[4], acc[5]); o[3] = pack2(acc[6], acc[7]);
        psum[ci] = o;
    }

    // ---- write sums back into mol (all gather reads are complete) ----
    __syncthreads();
    #pragma unroll
    for (int ci = 0; ci < 16; ++ci) {
        const int c = qd * 16 + ci;
        *(u32x4*)(molB + a * 1024 + ((c ^ a7) << 4)) = psum[ci];
    }
    __syncthreads();

    // ---- coalesced copy-out: wave covers one row's 1 KB per instruction ----
    const int chunk = tid & 63;
    char* dst = (char*)summed + (size_t)m * (NA * NF * 2);
    #pragma unroll
    for (int t = 0; t < 16; ++t) {
        const int row = t * 8 + (tid >> 6);    // wave-uniform row
        u32x4 v = *(const u32x4*)(molB + row * 1024 + ((chunk ^ (row & 7)) << 4));
        *(u32x4*)(dst + row * 1024 + chunk * 16) = v;
    }
}

// ---------------- kernel B: per-degree gathered GEMM ----------------
// BM=128, BN=256, BK=32. 512 threads / 8 waves (2m x 4n), wave tile 64x64.
// Triple-buffered, 2-tile-ahead counted-vmcnt pipeline, ONE barrier/K-step
// (verified R7/R9/R10). Stage swizzle 0-conflict (verified). XCD-bijective
// grid decode (verified, FETCH ~23 MB).
// NEW: LDS-transposed epilogue. Staging LDS is dead after the K-loop; dump
// acc as [row][256] f32 in two 64-row slices; each wave then reads one row
// and nt-stores it as 64 contiguous dwordx4 = 1 KB dense per instruction.
__global__ __launch_bounds__(512, 4) void gemm_deg(
    const __hip_bfloat16* __restrict__ summed, const __hip_bfloat16* __restrict__ Wt,
    const float* __restrict__ bias, const int* __restrict__ counts,
    const int* __restrict__ bucket, float* __restrict__ out) {
    const int L  = blockIdx.x + 24 * blockIdx.y;   // 0..3071
    const int q  = L >> 3;                          // per-XCD sequence
    const int p  = ((q >> 1) << 3) + (L & 7);       // (d, m-tile) pair, p%8 = XCD
    const int d  = p % ND;
    const int m0 = (p / ND) * 128;
    const int n0 = (q & 1) * 256;                   // 2 n-tiles consecutive per pair
    const int Md = counts[d];
    if (m0 >= Md) return;

    // manual carve: sA 3x8 KB | sB 3x16 KB | sRows; epilogue reuses [0,64 KB)
    __shared__ __align__(16) char smem[74240];
    char* const sAb   = smem;                 // 24576 B
    char* const sBb   = smem + 24576;         // 49152 B
    int*  const sRows = (int*)(smem + 73728); // 512 B

    const int tid = threadIdx.x;
    if (tid < 128) {
        int r = m0 + tid;
        sRows[tid] = (r < Md) ? bucket[d * NATOMS + r] : -1;
    }
    __syncthreads();

    const int lane = tid & 63;
    const int w    = tid >> 6;      // 0..7

    // staging coords: lane covers (row = w*16 + sr, 16B slot sl)
    const int sr = lane >> 2;       // 0..15
    const int sl = lane & 3;
    const int gseg = sl ^ ((sr >> 1) & 3);   // pre-swizzled global segment

    const char* smB = (const char*)summed;
    const char* wtB = (const char*)Wt + (size_t)(d * NC + n0) * 1024;
    int g0 = sRows[w * 16 + sr];
    const size_t gA0 = (size_t)((g0 < 0) ? 0 : g0) * 1024;   // dummy row 0
    const size_t gB0 = (size_t)(w * 16 + sr) * 1024;         // B rows 0..127
    const size_t gB1 = (size_t)(128 + w * 16 + sr) * 1024;   // B rows 128..255

    const int quad = lane >> 4, l16 = lane & 15;
    const int xr2  = (l16 >> 1) & 3;         // read-side swizzle
    const int wy = w >> 2, wx = w & 3;       // 2m x 4n wave grid

    f32x4 acc[4][4];
    #pragma unroll
    for (int i = 0; i < 4; ++i)
        #pragma unroll
        for (int j = 0; j < 4; ++j) acc[i][j] = (f32x4)0.0f;

    auto stage = [&](int buf, int kt) {
        const int koff = kt * 64 + gseg * 16;
        async16(smB + gA0 + koff, sAb + buf * 8192 + w * 1024);
        async16(wtB + gB0 + koff, sBb + buf * 16384 + w * 1024);
        async16(wtB + gB1 + koff, sBb + buf * 16384 + 8192 + w * 1024);
    };
    auto compute = [&](int buf) {
        const __hip_bfloat16* A  = (const __hip_bfloat16*)(sAb + buf * 8192);
        const __hip_bfloat16* Bm = (const __hip_bfloat16*)(sBb + buf * 16384);
        frag8 aF[4], bF[4];
        #pragma unroll
        for (int i = 0; i < 4; ++i)
            aF[i] = *(const frag8*)&A[(wy * 64 + i * 16 + l16) * 32 +
                                      ((quad ^ xr2) << 3)];
        #pragma unroll
        for (int j = 0; j < 4; ++j)
            bF[j] = *(const frag8*)&Bm[(wx * 64 + j * 16 + l16) * 32 +
                                       ((quad ^ xr2) << 3)];
        #pragma unroll
        for (int i = 0; i < 4; ++i)
            #pragma unroll
            for (int j = 0; j < 4; ++j)
                acc[i][j] = __builtin_amdgcn_mfma_f32_16x16x32_bf16(
                    aF[i], bF[j], acc[i][j], 0, 0, 0);
    };

    stage(0, 0);                                   // tile 0 -> buf 0
    stage(1, 1);                                   // tile 1 -> buf 1
    #pragma unroll
    for (int kt = 0; kt < NF / 32; ++kt) {
        if (kt < NF / 32 - 1)
            asm volatile("s_waitcnt vmcnt(3)" ::: "memory");  // tile kt landed
        else
            asm volatile("s_waitcnt vmcnt(0)" ::: "memory");
        __builtin_amdgcn_sched_barrier(0);
        __builtin_amdgcn_s_barrier();              // tile kt visible; buf kt+2 free
        if (kt + 2 < NF / 32) stage((kt + 2) % 3, kt + 2);
        __builtin_amdgcn_s_setprio(1);
        compute(kt % 3);
        __builtin_amdgcn_s_setprio(0);
    }

    // ---- LDS-transposed epilogue ----
    // bias chunk for this lane-slot (same cols for every row): 4 floats
    const int chunk = tid & 63;                    // float4 chunk within 256 cols
    const f32x4 bv = *(const f32x4*)&bias[d * NC + n0 + chunk * 4];
    float* cs = (float*)smem;                      // 64 rows x 256 cols = 64 KB

    #pragma unroll
    for (int s = 0; s < 2; ++s) {
        __syncthreads();           // K-loop done / previous slice reads done
        if (wy == s) {
            #pragma unroll
            for (int i = 0; i < 4; ++i)
                #pragma unroll
                for (int j = 0; j < 4; ++j)
                    #pragma unroll
                    for (int r = 0; r < 4; ++r)
                        cs[(i * 16 + quad * 4 + r) * 256 + wx * 64 + j * 16 + l16] =
                            acc[i][j][r];
        }
        __syncthreads();
        #pragma unroll
        for (int t = 0; t < 8; ++t) {
            const int row = t * 8 + (tid >> 6);    // wave-uniform row in slice
            const int g   = sRows[s * 64 + row];
            if (g >= 0) {
                f32x4 v = *(const f32x4*)&cs[row * 256 + chunk * 4];
                v += bv;
                __builtin_nontemporal_store(
                    v, (f32x4*)(out + (size_t)g * NC + n0 + chunk * 4));
            }
        }
    }
}

extern "C" void kernel_launch(void* const* d_in, const int* in_sizes, int n_in,
                              void* d_out, int out_size, void* d_ws, size_t ws_size,
                              hipStream_t stream) {
    const float* atoms = (const float*)d_in[0];
    const int*   bonds = (const int*)d_in[1];
    const float* W     = (const float*)d_in[2];
    const float* bias  = (const float*)d_in[3];
    float* out = (float*)d_out;

    // workspace layout
    char* ws = (char*)d_ws;
    int* counts = (int*)ws;                                   // 6 ints
    int* bucket = (int*)(ws + 1024);                          // 6*32768 ints = 786432 B
    __hip_bfloat16* Wt     = (__hip_bfloat16*)(ws + 1024 + 786432);            // 3 MB
    __hip_bfloat16* summed = (__hip_bfloat16*)(ws + 1024 + 786432 + 3145728);  // 32 MB

    hipMemsetAsync(counts, 0, 1024, stream);

    prep_misc<<<NT_TRANS + NT_BUCK, 256, 0, stream>>>(W, Wt, bonds, counts, bucket);

    sum_mol<<<NB, 512, 0, stream>>>(atoms, bonds, summed);

    gemm_deg<<<dim3(24, 128), 512, 0, stream>>>(
        summed, Wt, bias, counts, bucket, out);
}

// Round 9
// 165.787 us; speedup vs baseline: 1.3106x; 1.0051x over previous
//
#include <hip/hip_runtime.h>
#include <hip/hip_bf16.h>

// Problem: B=256, A=128, F=512, D=6, C=512
// out[b,a,:] = (atoms[b,a,:] + sum_j atoms[b,bonds[b,a,j],:]) @ W[deg] + bias[deg]
// deg = count(bonds != -1), in 0..5.
//
// R12b: R12 with the compile fix (__builtin_nontemporal_load needs an ext
//      vector type, not HIP float4 — use f32x4).
//      Design (unchanged from R12): kill the last random-access stream.
//      `summed` is stored BUCKET-PERMUTED: prep emits inv[g]=(d<<16)|r;
//      sum_mol scatters its dense 1 KB row-writes to dbase[d]+r; gemm's
//      A-stage becomes a pure CONTIGUOUS stream (rows dbase[d]+m0+r) ->
//      latency pipelined by MSHRs/DRAM pages instead of the LDS pipeline.
//      sRows kept only for the out scatter. Padding rows read the next
//      bucket (garbage rows, MFMA-independent, masked at store); 128 KB
//      slack after summed covers the tail.
//      Kept (verified): 3-buf counted-vmcnt(3) 1-barrier pipeline, 0-conflict
//      stage swizzle, XCD-bijective decode, LDS-transposed dense epilogues.

#define NB 256
#define NA 128
#define NF 512
#define ND 6
#define NC 512
#define NATOMS (NB * NA)   // 32768

#define NT_TRANS 1536      // transpose role blocks (16 x 16 x 6)
#define NT_BUCK  32        // bucket role blocks

typedef __attribute__((ext_vector_type(8))) short frag8;
typedef __attribute__((ext_vector_type(4))) float f32x4;
typedef __attribute__((ext_vector_type(4))) unsigned int u32x4;

static __device__ inline unsigned short f2bu(float f) {
    __hip_bfloat16 h = __float2bfloat16(f);
    return *reinterpret_cast<unsigned short*>(&h);
}
static __device__ inline unsigned int pack2(float a, float b) {
    return (unsigned int)f2bu(a) | ((unsigned int)f2bu(b) << 16);
}
static __device__ inline float b2f(unsigned short u) {
    __hip_bfloat16 h;
    *reinterpret_cast<unsigned short*>(&h) = u;
    return __bfloat162float(h);
}
static __device__ inline void async16(const void* g, void* l) {
    __builtin_amdgcn_global_load_lds(
        (const __attribute__((address_space(1))) void*)g,
        (__attribute__((address_space(3))) void*)l, 16, 0, 0);
}

// ---------------- kernel M: prep_misc (transpose_w | bucket_atoms) ----------
__global__ __launch_bounds__(256) void prep_misc(
    const float* __restrict__ W, __hip_bfloat16* __restrict__ Wt,
    const int* __restrict__ bonds, int* __restrict__ counts,
    int* __restrict__ bucket, int* __restrict__ inv) {
    const int bid = blockIdx.x;
    const int tid = threadIdx.x;
    __shared__ float t[32][33];
    __shared__ int lcnt[ND];
    __shared__ int lbase[ND];

    if (bid < NT_TRANS) {
        // ---- transpose role: W[d][f][c] f32 -> Wt[d][c][f] bf16 ----
        const int tx = tid & 31, ty = tid >> 5;           // 32 x 8
        const int c0 = (bid & 15) * 32;
        const int f0 = ((bid >> 4) & 15) * 32;
        const int d  = bid >> 8;
        #pragma unroll
        for (int r = 0; r < 32; r += 8)
            t[ty + r][tx] =
                W[((size_t)(d * NF + f0 + ty + r)) * NC + c0 + tx];
        __syncthreads();
        #pragma unroll
        for (int r = 0; r < 32; r += 8)
            Wt[((size_t)(d * NC + c0 + ty + r)) * NF + f0 + tx] =
                __float2bfloat16(t[tx][ty + r]);
        return;
    }
    // ---- bucket role: degree bucketing, LDS-aggregated; emits inverse ----
    const int b = bid - NT_TRANS;
    if (tid < ND) lcnt[tid] = 0;
    __syncthreads();
    int deg[4], loc[4], gg[4];
    #pragma unroll
    for (int i = 0; i < 4; ++i) {
        int g = b * 1024 + i * 256 + tid;
        gg[i] = g;
        int dg = 0;
        #pragma unroll
        for (int j = 0; j < ND; ++j) dg += (bonds[g * ND + j] >= 0);
        deg[i] = dg;
        loc[i] = atomicAdd(&lcnt[dg], 1);
    }
    __syncthreads();
    if (tid < ND) lbase[tid] = atomicAdd(&counts[tid], lcnt[tid]);
    __syncthreads();
    #pragma unroll
    for (int i = 0; i < 4; ++i) {
        const int r = lbase[deg[i]] + loc[i];
        bucket[deg[i] * NATOMS + r] = gg[i];
        inv[gg[i]] = (deg[i] << 16) | r;       // g -> (d, rank within bucket)
    }
}

// ---------------- kernel A: sum_mol — whole-molecule gather in LDS ----------
// One block per molecule. Stage 256 KB f32 molecule densely (nt loads) into
// 128 KB bf16 LDS (chunk XOR-swizzle), gather+sum 6 neighbours from LDS into
// registers, write sums back into mol, then copy out each row (1 KB dense
// per wave-instruction) to its BUCKET-PERMUTED position dbase[d] + r.
__global__ __launch_bounds__(512, 2) void sum_mol(
    const float* __restrict__ atoms, const int* __restrict__ bonds,
    const int* __restrict__ counts, const int* __restrict__ inv,
    __hip_bfloat16* __restrict__ summed) {
    __shared__ __align__(16) __hip_bfloat16 mol[NA * NF];   // 128 KB
    __shared__ int sdst[NA];
    char* molB = (char*)mol;
    const int m   = blockIdx.x;
    const int tid = threadIdx.x;

    // permuted destination row for each atom of this molecule
    if (tid < NA) {
        const int iv = inv[m * NA + tid];
        const int d  = iv >> 16, r = iv & 0xffff;
        int base = 0;
        #pragma unroll
        for (int k = 0; k < ND; ++k) base += (k < d) ? counts[k] : 0;
        sdst[tid] = base + r;
    }

    // ---- stage: dense coalesced nt read, swizzled LDS write ----
    const f32x4* a4 = (const f32x4*)atoms + (size_t)m * (NA * NF / 4);
    #pragma unroll 4
    for (int i = 0; i < 32; ++i) {
        f32x4 v = __builtin_nontemporal_load(&a4[i * 512 + tid]);
        const int r  = i * 4 + (tid >> 7);
        const int co = tid & 127;              // float4 index within row
        uint2 pk; pk.x = pack2(v[0], v[1]); pk.y = pack2(v[2], v[3]);
        *(uint2*)(molB + r * 1024 + (((co >> 1) ^ (r & 7)) << 4) + (co & 1) * 8) = pk;
    }
    __syncthreads();

    // ---- gather+sum from LDS into registers ----
    const int a  = tid >> 2;                   // atom 0..127
    const int qd = tid & 3;                    // quarter of the feature row
    const int* bd = bonds + (size_t)(m * NA + a) * ND;
    int   nb[ND], x7[ND];
    float msk[ND];
    #pragma unroll
    for (int j = 0; j < ND; ++j) {
        int n = bd[j];
        msk[j] = (n >= 0) ? 1.0f : 0.0f;
        nb[j]  = (n >= 0) ? n : 0;
        x7[j]  = nb[j] & 7;
    }
    const int a7 = a & 7;

    u32x4 psum[16];
    #pragma unroll
    for (int ci = 0; ci < 16; ++ci) {
        const int c = qd * 16 + ci;
        const frag8 s = *(const frag8*)(molB + a * 1024 + ((c ^ a7) << 4));
        float acc[8];
        #pragma unroll
        for (int e = 0; e < 8; ++e) acc[e] = b2f((unsigned short)s[e]);
        #pragma unroll
        for (int j = 0; j < ND; ++j) {
            const frag8 v = *(const frag8*)(molB + nb[j] * 1024 + ((c ^ x7[j]) << 4));
            #pragma unroll
            for (int e = 0; e < 8; ++e)
                acc[e] = fmaf(b2f((unsigned short)v[e]), msk[j], acc[e]);
        }
        u32x4 o;
        o[0] = pack2(acc[0], acc[1]); o[1] = pack2(acc[2], acc[3]);
        o[2] = pack2(acc[4], acc[5]); o[3] = pack2(acc[6], acc[7]);
        psum[ci] = o;
    }

    // ---- write sums back into mol (all gather reads are complete) ----
    __syncthreads();
    #pragma unroll
    for (int ci = 0; ci < 16; ++ci) {
        const int c = qd * 16 + ci;
        *(u32x4*)(molB + a * 1024 + ((c ^ a7) << 4)) = psum[ci];
    }
    __syncthreads();

    // ---- permuted copy-out: one wave = one row's 1 KB per instruction ----
    const int chunk = tid & 63;
    #pragma unroll
    for (int t = 0; t < 16; ++t) {
        const int row = t * 8 + (tid >> 6);    // wave-uniform row (atom)
        u32x4 v = *(const u32x4*)(molB + row * 1024 + ((chunk ^ (row & 7)) << 4));
        char* dst = (char*)summed + (size_t)sdst[row] * 1024;
        *(u32x4*)(dst + chunk * 16) = v;
    }
}

// ---------------- kernel B: per-degree GEMM, streaming A ----------------
// BM=128, BN=256, BK=32. 512 threads / 8 waves (2m x 4n), wave tile 64x64.
// A rows are now CONTIGUOUS in the permuted summed: gA = (dbase+m0+row)*1KB.
// Triple-buffered, 2-tile-ahead counted-vmcnt pipeline, ONE barrier/K-step
// (verified). 0-conflict stage swizzle (verified). XCD-bijective decode
// (verified, FETCH ~23 MB). LDS-transposed dense nt epilogue (verified).
__global__ __launch_bounds__(512, 4) void gemm_deg(
    const __hip_bfloat16* __restrict__ summed, const __hip_bfloat16* __restrict__ Wt,
    const float* __restrict__ bias, const int* __restrict__ counts,
    const int* __restrict__ bucket, float* __restrict__ out) {
    const int L  = blockIdx.x + 24 * blockIdx.y;   // 0..3071
    const int q  = L >> 3;                          // per-XCD sequence
    const int p  = ((q >> 1) << 3) + (L & 7);       // (d, m-tile) pair, p%8 = XCD
    const int d  = p % ND;
    const int m0 = (p / ND) * 128;
    const int n0 = (q & 1) * 256;                   // 2 n-tiles consecutive per pair
    const int Md = counts[d];
    if (m0 >= Md) return;
    int dBase = 0;
    #pragma unroll
    for (int k = 0; k < ND; ++k) dBase += (k < d) ? counts[k] : 0;

    // manual carve: sA 3x8 KB | sB 3x16 KB | sRows; epilogue reuses [0,64 KB)
    __shared__ __align__(16) char smem[74240];
    char* const sAb   = smem;                 // 24576 B
    char* const sBb   = smem + 24576;         // 49152 B
    int*  const sRows = (int*)(smem + 73728); // 512 B

    const int tid = threadIdx.x;
    if (tid < 128) {
        int r = m0 + tid;
        sRows[tid] = (r < Md) ? bucket[d * NATOMS + r] : -1;
    }
    __syncthreads();

    const int lane = tid & 63;
    const int w    = tid >> 6;      // 0..7

    // staging coords: lane covers (row = w*16 + sr, 16B slot sl)
    const int sr = lane >> 2;       // 0..15
    const int sl = lane & 3;
    const int gseg = sl ^ ((sr >> 1) & 3);   // pre-swizzled global segment

    const char* smB = (const char*)summed;
    const char* wtB = (const char*)Wt + (size_t)(d * NC + n0) * 1024;
    const size_t gA0 = (size_t)(dBase + m0 + w * 16 + sr) * 1024;  // STREAMING
    const size_t gB0 = (size_t)(w * 16 + sr) * 1024;         // B rows 0..127
    const size_t gB1 = (size_t)(128 + w * 16 + sr) * 1024;   // B rows 128..255

    const int quad = lane >> 4, l16 = lane & 15;
    const int xr2  = (l16 >> 1) & 3;         // read-side swizzle
    const int wy = w >> 2, wx = w & 3;       // 2m x 4n wave grid

    f32x4 acc[4][4];
    #pragma unroll
    for (int i = 0; i < 4; ++i)
        #pragma unroll
        for (int j = 0; j < 4; ++j) acc[i][j] = (f32x4)0.0f;

    auto stage = [&](int buf, int kt) {
        const int koff = kt * 64 + gseg * 16;
        async16(smB + gA0 + koff, sAb + buf * 8192 + w * 1024);
        async16(wtB + gB0 + koff, sBb + buf * 16384 + w * 1024);
        async16(wtB + gB1 + koff, sBb + buf * 16384 + 8192 + w * 1024);
    };
    auto compute = [&](int buf) {
        const __hip_bfloat16* A  = (const __hip_bfloat16*)(sAb + buf * 8192);
        const __hip_bfloat16* Bm = (const __hip_bfloat16*)(sBb + buf * 16384);
        frag8 aF[4], bF[4];
        #pragma unroll
        for (int i = 0; i < 4; ++i)
            aF[i] = *(const frag8*)&A[(wy * 64 + i * 16 + l16) * 32 +
                                      ((quad ^ xr2) << 3)];
        #pragma unroll
        for (int j = 0; j < 4; ++j)
            bF[j] = *(const frag8*)&Bm[(wx * 64 + j * 16 + l16) * 32 +
                                       ((quad ^ xr2) << 3)];
        #pragma unroll
        for (int i = 0; i < 4; ++i)
            #pragma unroll
            for (int j = 0; j < 4; ++j)
                acc[i][j] = __builtin_amdgcn_mfma_f32_16x16x32_bf16(
                    aF[i], bF[j], acc[i][j], 0, 0, 0);
    };

    stage(0, 0);                                   // tile 0 -> buf 0
    stage(1, 1);                                   // tile 1 -> buf 1
    #pragma unroll
    for (int kt = 0; kt < NF / 32; ++kt) {
        if (kt < NF / 32 - 1)
            asm volatile("s_waitcnt vmcnt(3)" ::: "memory");  // tile kt landed
        else
            asm volatile("s_waitcnt vmcnt(0)" ::: "memory");
        __builtin_amdgcn_sched_barrier(0);
        __builtin_amdgcn_s_barrier();              // tile kt visible; buf kt+2 free
        if (kt + 2 < NF / 32) stage((kt + 2) % 3, kt + 2);
        __builtin_amdgcn_s_setprio(1);
        compute(kt % 3);
        __builtin_amdgcn_s_setprio(0);
    }

    // ---- LDS-transposed dense epilogue (verified R11) ----
    const int chunk = tid & 63;                    // float4 chunk within 256 cols
    const f32x4 bv = *(const f32x4*)&bias[d * NC + n0 + chunk * 4];
    float* cs = (float*)smem;                      // 64 rows x 256 cols = 64 KB

    #pragma unroll
    for (int s = 0; s < 2; ++s) {
        __syncthreads();           // K-loop done / previous slice reads done
        if (wy == s) {
            #pragma unroll
            for (int i = 0; i < 4; ++i)
                #pragma unroll
                for (int j = 0; j < 4; ++j)
                    #pragma unroll
                    for (int r = 0; r < 4; ++r)
                        cs[(i * 16 + quad * 4 + r) * 256 + wx * 64 + j * 16 + l16] =
                            acc[i][j][r];
        }
        __syncthreads();
        #pragma unroll
        for (int t = 0; t < 8; ++t) {
            const int row = t * 8 + (tid >> 6);    // wave-uniform row in slice
            const int g   = sRows[s * 64 + row];
            if (g >= 0) {
                f32x4 v = *(const f32x4*)&cs[row * 256 + chunk * 4];
                v += bv;
                __builtin_nontemporal_store(
                    v, (f32x4*)(out + (size_t)g * NC + n0 + chunk * 4));
            }
        }
    }
}

extern "C" void kernel_launch(void* const* d_in, const int* in_sizes, int n_in,
                              void* d_out, int out_size, void* d_ws, size_t ws_size,
                              hipStream_t stream) {
    const float* atoms = (const float*)d_in[0];
    const int*   bonds = (const int*)d_in[1];
    const float* W     = (const float*)d_in[2];
    const float* bias  = (const float*)d_in[3];
    float* out = (float*)d_out;

    // workspace layout
    char* ws = (char*)d_ws;
    int* counts = (int*)ws;                                   // 1024 B
    int* bucket = (int*)(ws + 1024);                          // 786432 B
    int* inv    = (int*)(ws + 1024 + 786432);                 // 131072 B
    __hip_bfloat16* Wt     = (__hip_bfloat16*)(ws + 918528);            // 3 MB
    __hip_bfloat16* summed = (__hip_bfloat16*)(ws + 918528 + 3145728);  // 32 MB + 128 KB slack

    (void)hipMemsetAsync(counts, 0, 1024, stream);

    prep_misc<<<NT_TRANS + NT_BUCK, 256, 0, stream>>>(
        W, Wt, bonds, counts, bucket, inv);

    sum_mol<<<NB, 512, 0, stream>>>(atoms, bonds, counts, inv, summed);

    gemm_deg<<<dim3(24, 128), 512, 0, stream>>>(
        summed, Wt, bias, counts, bucket, out);
}

// Round 10
// 165.067 us; speedup vs baseline: 1.3163x; 1.0044x over previous
//
#include <hip/hip_runtime.h>
#include <hip/hip_bf16.h>

// Problem: B=256, A=128, F=512, D=6, C=512
// out[b,a,:] = (atoms[b,a,:] + sum_j atoms[b,bonds[b,a,j],:]) @ W[deg] + bias[deg]
// deg = count(bonds != -1), in 0..5.
//
// R13: transaction-count round (R12b: writes are ideal 66.6 MB; steady gemm
//      ~30us vs ~16 floor; remaining pacer modeled as L1/L2 transactions of
//      staging: 16-row x 64B strided wave-insts = half-used lines).
//      (1) Wt stored K-MAJOR [d][kt=16][c=512][32 bf16]: each B-stage
//          wave-instruction now reads 1 KB CONTIGUOUS (dense 128B lines,
//          ~2x fewer tx on 2 of the 3 loads/step). Swizzle preserved via
//          pre-swizzled source segment (rule 21).
//      (2) gemm epilogue cs stride 256->260 f32: quad-row write stride
//          1040f ≡ 16 mod 32 -> 2-way (free); kills the 530K conflicts.
//      Kept (verified): bucket-permuted summed (streaming A), 3-buf
//      counted-vmcnt(3) 1-barrier pipeline, 0-conflict stage swizzle,
//      XCD decode, LDS-transposed dense nt epilogues, sum_mol LDS gather.

#define NB 256
#define NA 128
#define NF 512
#define ND 6
#define NC 512
#define NATOMS (NB * NA)   // 32768

#define NT_TRANS 1536      // transpose role blocks (16 x 16 x 6)
#define NT_BUCK  32        // bucket role blocks

typedef __attribute__((ext_vector_type(8))) short frag8;
typedef __attribute__((ext_vector_type(4))) float f32x4;
typedef __attribute__((ext_vector_type(4))) unsigned int u32x4;

static __device__ inline unsigned short f2bu(float f) {
    __hip_bfloat16 h = __float2bfloat16(f);
    return *reinterpret_cast<unsigned short*>(&h);
}
static __device__ inline unsigned int pack2(float a, float b) {
    return (unsigned int)f2bu(a) | ((unsigned int)f2bu(b) << 16);
}
static __device__ inline float b2f(unsigned short u) {
    __hip_bfloat16 h;
    *reinterpret_cast<unsigned short*>(&h) = u;
    return __bfloat162float(h);
}
static __device__ inline void async16(const void* g, void* l) {
    __builtin_amdgcn_global_load_lds(
        (const __attribute__((address_space(1))) void*)g,
        (__attribute__((address_space(3))) void*)l, 16, 0, 0);
}

// ---------------- kernel M: prep_misc (transpose_w | bucket_atoms) ----------
// Wt K-major layout: elem (d, c, f) -> d*262144 + (f>>5)*16384 + c*32 + (f&31)
__global__ __launch_bounds__(256) void prep_misc(
    const float* __restrict__ W, __hip_bfloat16* __restrict__ Wt,
    const int* __restrict__ bonds, int* __restrict__ counts,
    int* __restrict__ bucket, int* __restrict__ inv) {
    const int bid = blockIdx.x;
    const int tid = threadIdx.x;
    __shared__ float t[32][33];
    __shared__ int lcnt[ND];
    __shared__ int lbase[ND];

    if (bid < NT_TRANS) {
        // ---- transpose role: W[d][f][c] f32 -> Wt K-major bf16 ----
        const int tx = tid & 31, ty = tid >> 5;           // 32 x 8
        const int c0 = (bid & 15) * 32;
        const int f0 = ((bid >> 4) & 15) * 32;
        const int d  = bid >> 8;
        #pragma unroll
        for (int r = 0; r < 32; r += 8)
            t[ty + r][tx] =
                W[((size_t)(d * NF + f0 + ty + r)) * NC + c0 + tx];
        __syncthreads();
        // write: c = c0+ty+r, f = f0+tx; f>>5 = f0>>5 (f0 % 32 == 0)
        const size_t kbase = (size_t)d * 262144 + (size_t)(f0 >> 5) * 16384;
        #pragma unroll
        for (int r = 0; r < 32; r += 8)
            Wt[kbase + (size_t)(c0 + ty + r) * 32 + tx] =
                __float2bfloat16(t[tx][ty + r]);
        return;
    }
    // ---- bucket role: degree bucketing, LDS-aggregated; emits inverse ----
    const int b = bid - NT_TRANS;
    if (tid < ND) lcnt[tid] = 0;
    __syncthreads();
    int deg[4], loc[4], gg[4];
    #pragma unroll
    for (int i = 0; i < 4; ++i) {
        int g = b * 1024 + i * 256 + tid;
        gg[i] = g;
        int dg = 0;
        #pragma unroll
        for (int j = 0; j < ND; ++j) dg += (bonds[g * ND + j] >= 0);
        deg[i] = dg;
        loc[i] = atomicAdd(&lcnt[dg], 1);
    }
    __syncthreads();
    if (tid < ND) lbase[tid] = atomicAdd(&counts[tid], lcnt[tid]);
    __syncthreads();
    #pragma unroll
    for (int i = 0; i < 4; ++i) {
        const int r = lbase[deg[i]] + loc[i];
        bucket[deg[i] * NATOMS + r] = gg[i];
        inv[gg[i]] = (deg[i] << 16) | r;       // g -> (d, rank within bucket)
    }
}

// ---------------- kernel A: sum_mol — whole-molecule gather in LDS ----------
// One block per molecule. Stage 256 KB f32 molecule densely (nt loads) into
// 128 KB bf16 LDS (chunk XOR-swizzle), gather+sum 6 neighbours from LDS into
// registers, write sums back into mol, then copy out each row (1 KB dense
// per wave-instruction) to its BUCKET-PERMUTED position dbase[d] + r.
__global__ __launch_bounds__(512, 2) void sum_mol(
    const float* __restrict__ atoms, const int* __restrict__ bonds,
    const int* __restrict__ counts, const int* __restrict__ inv,
    __hip_bfloat16* __restrict__ summed) {
    __shared__ __align__(16) __hip_bfloat16 mol[NA * NF];   // 128 KB
    __shared__ int sdst[NA];
    char* molB = (char*)mol;
    const int m   = blockIdx.x;
    const int tid = threadIdx.x;

    // permuted destination row for each atom of this molecule
    if (tid < NA) {
        const int iv = inv[m * NA + tid];
        const int d  = iv >> 16, r = iv & 0xffff;
        int base = 0;
        #pragma unroll
        for (int k = 0; k < ND; ++k) base += (k < d) ? counts[k] : 0;
        sdst[tid] = base + r;
    }

    // ---- stage: dense coalesced nt read, swizzled LDS write ----
    const f32x4* a4 = (const f32x4*)atoms + (size_t)m * (NA * NF / 4);
    #pragma unroll 4
    for (int i = 0; i < 32; ++i) {
        f32x4 v = __builtin_nontemporal_load(&a4[i * 512 + tid]);
        const int r  = i * 4 + (tid >> 7);
        const int co = tid & 127;              // float4 index within row
        uint2 pk; pk.x = pack2(v[0], v[1]); pk.y = pack2(v[2], v[3]);
        *(uint2*)(molB + r * 1024 + (((co >> 1) ^ (r & 7)) << 4) + (co & 1) * 8) = pk;
    }
    __syncthreads();

    // ---- gather+sum from LDS into registers ----
    const int a  = tid >> 2;                   // atom 0..127
    const int qd = tid & 3;                    // quarter of the feature row
    const int* bd = bonds + (size_t)(m * NA + a) * ND;
    int   nb[ND], x7[ND];
    float msk[ND];
    #pragma unroll
    for (int j = 0; j < ND; ++j) {
        int n = bd[j];
        msk[j] = (n >= 0) ? 1.0f : 0.0f;
        nb[j]  = (n >= 0) ? n : 0;
        x7[j]  = nb[j] & 7;
    }
    const int a7 = a & 7;

    u32x4 psum[16];
    #pragma unroll
    for (int ci = 0; ci < 16; ++ci) {
        const int c = qd * 16 + ci;
        const frag8 s = *(const frag8*)(molB + a * 1024 + ((c ^ a7) << 4));
        float acc[8];
        #pragma unroll
        for (int e = 0; e < 8; ++e) acc[e] = b2f((unsigned short)s[e]);
        #pragma unroll
        for (int j = 0; j < ND; ++j) {
            const frag8 v = *(const frag8*)(molB + nb[j] * 1024 + ((c ^ x7[j]) << 4));
            #pragma unroll
            for (int e = 0; e < 8; ++e)
                acc[e] = fmaf(b2f((unsigned short)v[e]), msk[j], acc[e]);
        }
        u32x4 o;
        o[0] = pack2(acc[0], acc[1]); o[1] = pack2(acc[2], acc[3]);
        o[2] = pack2(acc[4], acc[5]); o[3] = pack2(acc[6], acc[7]);
        psum[ci] = o;
    }

    // ---- write sums back into mol (all gather reads are complete) ----
    __syncthreads();
    #pragma unroll
    for (int ci = 0; ci < 16; ++ci) {
        const int c = qd * 16 + ci;
        *(u32x4*)(molB + a * 1024 + ((c ^ a7) << 4)) = psum[ci];
    }
    __syncthreads();

    // ---- permuted copy-out: one wave = one row's 1 KB per instruction ----
    const int chunk = tid & 63;
    #pragma unroll
    for (int t = 0; t < 16; ++t) {
        const int row = t * 8 + (tid >> 6);    // wave-uniform row (atom)
        u32x4 v = *(const u32x4*)(molB + row * 1024 + ((chunk ^ (row & 7)) << 4));
        char* dst = (char*)summed + (size_t)sdst[row] * 1024;
        *(u32x4*)(dst + chunk * 16) = v;
    }
}

// ---------------- kernel B: per-degree GEMM, streaming A, K-major B --------
// BM=128, BN=256, BK=32. 512 threads / 8 waves (2m x 4n), wave tile 64x64.
// A rows CONTIGUOUS in permuted summed; B K-major: per-step B stage insts
// read 1 KB contiguous (dense lines). 3-buf counted-vmcnt(3) 1-barrier
// pipeline (verified). 0-conflict stage swizzle (verified). XCD decode
// (verified). LDS-transposed dense nt epilogue, cs stride 260 (conflict-free).
__global__ __launch_bounds__(512, 4) void gemm_deg(
    const __hip_bfloat16* __restrict__ summed, const __hip_bfloat16* __restrict__ Wt,
    const float* __restrict__ bias, const int* __restrict__ counts,
    const int* __restrict__ bucket, float* __restrict__ out) {
    const int L  = blockIdx.x + 24 * blockIdx.y;   // 0..3071
    const int q  = L >> 3;                          // per-XCD sequence
    const int p  = ((q >> 1) << 3) + (L & 7);       // (d, m-tile) pair, p%8 = XCD
    const int d  = p % ND;
    const int m0 = (p / ND) * 128;
    const int n0 = (q & 1) * 256;                   // 2 n-tiles consecutive per pair
    const int Md = counts[d];
    if (m0 >= Md) return;
    int dBase = 0;
    #pragma unroll
    for (int k = 0; k < ND; ++k) dBase += (k < d) ? counts[k] : 0;

    // manual carve: sA 3x8 KB | sB 3x16 KB | sRows; epilogue reuses [0,66.6 KB)
    __shared__ __align__(16) char smem[74240];
    char* const sAb   = smem;                 // 24576 B
    char* const sBb   = smem + 24576;         // 49152 B
    int*  const sRows = (int*)(smem + 73728); // 512 B

    const int tid = threadIdx.x;
    if (tid < 128) {
        int r = m0 + tid;
        sRows[tid] = (r < Md) ? bucket[d * NATOMS + r] : -1;
    }
    __syncthreads();

    const int lane = tid & 63;
    const int w    = tid >> 6;      // 0..7

    // staging coords: lane covers (row = base + sr, 16B slot sl)
    const int sr = lane >> 2;       // 0..15
    const int sl = lane & 3;
    const int gseg = sl ^ ((sr >> 1) & 3);   // pre-swizzled global segment

    const char* smB = (const char*)summed;
    const char* wtB = (const char*)Wt + (size_t)d * 524288;  // K-major base
    const size_t gA0 = (size_t)(dBase + m0 + w * 16 + sr) * 1024;  // STREAMING
    // K-major B: slab kt at kt*32768; row n at n*64; rows n0 + k*128 + w*16+sr
    const size_t gBr0 = (size_t)(n0 + w * 16 + sr) * 64;
    const size_t gBr1 = (size_t)(n0 + 128 + w * 16 + sr) * 64;

    const int quad = lane >> 4, l16 = lane & 15;
    const int xr2  = (l16 >> 1) & 3;         // read-side swizzle
    const int wy = w >> 2, wx = w & 3;       // 2m x 4n wave grid

    f32x4 acc[4][4];
    #pragma unroll
    for (int i = 0; i < 4; ++i)
        #pragma unroll
        for (int j = 0; j < 4; ++j) acc[i][j] = (f32x4)0.0f;

    auto stage = [&](int buf, int kt) {
        async16(smB + gA0 + kt * 64 + gseg * 16, sAb + buf * 8192 + w * 1024);
        const char* slab = wtB + kt * 32768;
        async16(slab + gBr0 + gseg * 16, sBb + buf * 16384 + w * 1024);
        async16(slab + gBr1 + gseg * 16, sBb + buf * 16384 + 8192 + w * 1024);
    };
    auto compute = [&](int buf) {
        const __hip_bfloat16* A  = (const __hip_bfloat16*)(sAb + buf * 8192);
        const __hip_bfloat16* Bm = (const __hip_bfloat16*)(sBb + buf * 16384);
        frag8 aF[4], bF[4];
        #pragma unroll
        for (int i = 0; i < 4; ++i)
            aF[i] = *(const frag8*)&A[(wy * 64 + i * 16 + l16) * 32 +
                                      ((quad ^ xr2) << 3)];
        #pragma unroll
        for (int j = 0; j < 4; ++j)
            bF[j] = *(const frag8*)&Bm[(wx * 64 + j * 16 + l16) * 32 +
                                       ((quad ^ xr2) << 3)];
        #pragma unroll
        for (int i = 0; i < 4; ++i)
            #pragma unroll
            for (int j = 0; j < 4; ++j)
                acc[i][j] = __builtin_amdgcn_mfma_f32_16x16x32_bf16(
                    aF[i], bF[j], acc[i][j], 0, 0, 0);
    };

    stage(0, 0);                                   // tile 0 -> buf 0
    stage(1, 1);                                   // tile 1 -> buf 1
    #pragma unroll
    for (int kt = 0; kt < NF / 32; ++kt) {
        if (kt < NF / 32 - 1)
            asm volatile("s_waitcnt vmcnt(3)" ::: "memory");  // tile kt landed
        else
            asm volatile("s_waitcnt vmcnt(0)" ::: "memory");
        __builtin_amdgcn_sched_barrier(0);
        __builtin_amdgcn_s_barrier();              // tile kt visible; buf kt+2 free
        if (kt + 2 < NF / 32) stage((kt + 2) % 3, kt + 2);
        __builtin_amdgcn_s_setprio(1);
        compute(kt % 3);
        __builtin_amdgcn_s_setprio(0);
    }

    // ---- LDS-transposed dense epilogue; cs stride 260 (2-way max = free) ----
    const int chunk = tid & 63;                    // float4 chunk within 256 cols
    const f32x4 bv = *(const f32x4*)&bias[d * NC + n0 + chunk * 4];
    float* cs = (float*)smem;                      // 64 rows x 260 f32 = 66.6 KB

    #pragma unroll
    for (int s = 0; s < 2; ++s) {
        __syncthreads();           // K-loop done / previous slice reads done
        if (wy == s) {
            #pragma unroll
            for (int i = 0; i < 4; ++i)
                #pragma unroll
                for (int j = 0; j < 4; ++j)
                    #pragma unroll
                    for (int r = 0; r < 4; ++r)
                        cs[(i * 16 + quad * 4 + r) * 260 + wx * 64 + j * 16 + l16] =
                            acc[i][j][r];
        }
        __syncthreads();
        #pragma unroll
        for (int t = 0; t < 8; ++t) {
            const int row = t * 8 + (tid >> 6);    // wave-uniform row in slice
            const int g   = sRows[s * 64 + row];
            if (g >= 0) {
                f32x4 v = *(const f32x4*)&cs[row * 260 + chunk * 4];
                v += bv;
                __builtin_nontemporal_store(
                    v, (f32x4*)(out + (size_t)g * NC + n0 + chunk * 4));
            }
        }
    }
}

extern "C" void kernel_launch(void* const* d_in, const int* in_sizes, int n_in,
                              void* d_out, int out_size, void* d_ws, size_t ws_size,
                              hipStream_t stream) {
    const float* atoms = (const float*)d_in[0];
    const int*   bonds = (const int*)d_in[1];
    const float* W     = (const float*)d_in[2];
    const float* bias  = (const float*)d_in[3];
    float* out = (float*)d_out;

    // workspace layout
    char* ws = (char*)d_ws;
    int* counts = (int*)ws;                                   // 1024 B
    int* bucket = (int*)(ws + 1024);                          // 786432 B
    int* inv    = (int*)(ws + 1024 + 786432);                 // 131072 B
    __hip_bfloat16* Wt     = (__hip_bfloat16*)(ws + 918528);            // 3 MB
    __hip_bfloat16* summed = (__hip_bfloat16*)(ws + 918528 + 3145728);  // 32 MB + 128 KB slack

    (void)hipMemsetAsync(counts, 0, 1024, stream);

    prep_misc<<<NT_TRANS + NT_BUCK, 256, 0, stream>>>(
        W, Wt, bonds, counts, bucket, inv);

    sum_mol<<<NB, 512, 0, stream>>>(atoms, bonds, counts, inv, summed);

    gemm_deg<<<dim3(24, 128), 512, 0, stream>>>(
        summed, Wt, bias, counts, bucket, out);
}